// Round 1
// baseline (3115.226 us; speedup 1.0000x reference)
//
#include <hip/hip_runtime.h>

#define D 128
#define TM 16

// ---------------- CSR build ----------------

__global__ void hist_kernel(const int* __restrict__ dst, int* __restrict__ deg, int E) {
    int i = blockIdx.x * blockDim.x + threadIdx.x;
    if (i < E) atomicAdd(&deg[dst[i]], 1);
}

__global__ void scan_kernel(const int* __restrict__ deg, int* __restrict__ row_start,
                            int* __restrict__ cursor, float* __restrict__ inv_deg,
                            int n, int n_edges) {
    __shared__ int tmp[1024];
    __shared__ int carry_s;
    if (threadIdx.x == 0) carry_s = 0;
    __syncthreads();
    int nchunk = (n + 1023) / 1024;
    for (int c = 0; c < nchunk; ++c) {
        int i = c * 1024 + threadIdx.x;
        int v = (i < n) ? deg[i] : 0;
        tmp[threadIdx.x] = v;
        __syncthreads();
        for (int off = 1; off < 1024; off <<= 1) {
            int t = 0;
            if (threadIdx.x >= off) t = tmp[threadIdx.x - off];
            __syncthreads();
            if (threadIdx.x >= off) tmp[threadIdx.x] += t;
            __syncthreads();
        }
        int incl = tmp[threadIdx.x];
        int excl = incl - v;
        int base = carry_s;
        if (i < n) {
            row_start[i] = base + excl;
            cursor[i]    = base + excl;
            inv_deg[i]   = 1.0f / fmaxf((float)v, 1.0f);
        }
        __syncthreads();
        if (threadIdx.x == 1023) carry_s += tmp[1023];
        __syncthreads();
    }
    if (threadIdx.x == 0) row_start[n] = n_edges;
}

__global__ void scatter_kernel(const int* __restrict__ src, const int* __restrict__ dst,
                               int* __restrict__ cursor, int* __restrict__ csr, int E) {
    int i = blockIdx.x * blockDim.x + threadIdx.x;
    if (i < E) {
        int d = dst[i];
        int p = atomicAdd(&cursor[d], 1);
        csr[p] = src[i];
    }
}

// ---------------- weight transpose (W[l][f][k] -> Wt[l][k][f]) ----------------

__global__ void transpose_w(const float* __restrict__ Wl, const float* __restrict__ Wr,
                            float* __restrict__ Wlt, float* __restrict__ Wrt, int total) {
    int i = blockIdx.x * blockDim.x + threadIdx.x;
    if (i < total) {
        int l = i >> 14;
        int r = i & 16383;
        int f = r >> 7;
        int k = r & 127;
        int o = (l << 14) + (k << 7) + f;
        Wlt[o] = Wl[i];
        Wrt[o] = Wr[i];
    }
}

// ---------------- fused SAGE layer: gather-mean + dual GEMM + bias + relu ----------------

__launch_bounds__(256, 4)
__global__ void sage_layer(const float* __restrict__ xin, float* __restrict__ xout,
                           const int* __restrict__ row_start, const int* __restrict__ csr,
                           const float* __restrict__ inv_deg,
                           const float* __restrict__ Wlt, const float* __restrict__ Wrt,
                           const float* __restrict__ bl, int n_nodes) {
    __shared__ __align__(16) float A[TM][D];
    __shared__ __align__(16) float X[TM][D];
    int block0 = blockIdx.x * TM;
    int tid = threadIdx.x;

    // Phase A: two 128-thread groups gather alternating nodes.
    {
        int f = tid & 127;
        int g = tid >> 7;  // 0 or 1
        for (int j = g; j < TM; j += 2) {
            int n = block0 + j;
            float s = 0.f, xv = 0.f, idg = 1.f;
            if (n < n_nodes) {
                int e0 = row_start[n], e1 = row_start[n + 1];
                for (int e = e0; e < e1; ++e) {
                    int sidx = csr[e];
                    s += xin[(size_t)sidx * D + f];
                }
                idg = inv_deg[n];
                xv = xin[(size_t)n * D + f];
            }
            A[j][f] = s * idg;
            X[j][f] = xv;
        }
    }
    __syncthreads();

    // Phase B: thread tile = 2 nodes x 4 features.
    int tf = tid & 31;        // feature group: f0 = tf*4
    int tn = tid >> 5;        // 0..7
    int j0 = tn * 2;
    const float4* Wlt4 = (const float4*)Wlt;
    const float4* Wrt4 = (const float4*)Wrt;
    float4 bv = ((const float4*)bl)[tf];
    float4 o0 = bv, o1 = bv;
    const float4* A0 = (const float4*)A[j0];
    const float4* A1 = (const float4*)A[j0 + 1];
    const float4* X0 = (const float4*)X[j0];
    const float4* X1 = (const float4*)X[j0 + 1];

    #pragma unroll 4
    for (int kk = 0; kk < 32; ++kk) {
        float4 a0 = A0[kk], a1 = A1[kk], x0 = X0[kk], x1 = X1[kk];
        #pragma unroll
        for (int c = 0; c < 4; ++c) {
            int k = kk * 4 + c;
            float4 wl = Wlt4[k * 32 + tf];
            float4 wr = Wrt4[k * 32 + tf];
            float ac0 = (&a0.x)[c], ac1 = (&a1.x)[c];
            float xc0 = (&x0.x)[c], xc1 = (&x1.x)[c];
            o0.x += wl.x * ac0 + wr.x * xc0;
            o0.y += wl.y * ac0 + wr.y * xc0;
            o0.z += wl.z * ac0 + wr.z * xc0;
            o0.w += wl.w * ac0 + wr.w * xc0;
            o1.x += wl.x * ac1 + wr.x * xc1;
            o1.y += wl.y * ac1 + wr.y * xc1;
            o1.z += wl.z * ac1 + wr.z * xc1;
            o1.w += wl.w * ac1 + wr.w * xc1;
        }
    }

    int n0 = block0 + j0, n1 = n0 + 1;
    if (n0 < n_nodes) {
        float4 r;
        r.x = fmaxf(o0.x, 0.f); r.y = fmaxf(o0.y, 0.f);
        r.z = fmaxf(o0.z, 0.f); r.w = fmaxf(o0.w, 0.f);
        ((float4*)xout)[(size_t)n0 * 32 + tf] = r;
    }
    if (n1 < n_nodes) {
        float4 r;
        r.x = fmaxf(o1.x, 0.f); r.y = fmaxf(o1.y, 0.f);
        r.z = fmaxf(o1.z, 0.f); r.w = fmaxf(o1.w, 0.f);
        ((float4*)xout)[(size_t)n1 * 32 + tf] = r;
    }
}

extern "C" void kernel_launch(void* const* d_in, const int* in_sizes, int n_in,
                              void* d_out, int out_size, void* d_ws, size_t ws_size,
                              hipStream_t stream) {
    const float* x  = (const float*)d_in[0];
    const int*  edge = (const int*)d_in[1];
    const float* Wl = (const float*)d_in[2];
    const float* bl = (const float*)d_in[3];
    const float* Wr = (const float*)d_in[4];

    int N = in_sizes[0] / D;
    int E = in_sizes[1] / 2;
    int L = in_sizes[3] / D;
    const int* srcp = edge;
    const int* dstp = edge + E;

    char* w = (char*)d_ws;
    auto alloc = [&](size_t bytes) {
        char* p = w;
        w += (bytes + 255) & ~(size_t)255;
        return p;
    };
    int*   deg       = (int*)alloc((size_t)N * 4);
    int*   row_start = (int*)alloc((size_t)(N + 1) * 4);
    int*   cursor    = (int*)alloc((size_t)N * 4);
    int*   csr       = (int*)alloc((size_t)E * 4);
    float* invdeg    = (float*)alloc((size_t)N * 4);
    float* wlt       = (float*)alloc((size_t)L * D * D * 4);
    float* wrt       = (float*)alloc((size_t)L * D * D * 4);
    float* buf0      = (float*)alloc((size_t)N * D * 4);

    hipMemsetAsync(deg, 0, (size_t)N * 4, stream);
    hist_kernel<<<(E + 255) / 256, 256, 0, stream>>>(dstp, deg, E);
    scan_kernel<<<1, 1024, 0, stream>>>(deg, row_start, cursor, invdeg, N, E);
    scatter_kernel<<<(E + 255) / 256, 256, 0, stream>>>(srcp, dstp, cursor, csr, E);
    int tw = L * D * D;
    transpose_w<<<(tw + 255) / 256, 256, 0, stream>>>(Wl, Wr, wlt, wrt, tw);

    float* out = (float*)d_out;
    const float* cur = x;
    int nb = (N + TM - 1) / TM;
    for (int l = 0; l < L; ++l) {
        float* o = (l & 1) ? out : buf0;
        if (l == L - 1) o = out;
        sage_layer<<<nb, 256, 0, stream>>>(cur, o, row_start, csr, invdeg,
                                           wlt + (size_t)l * D * D,
                                           wrt + (size_t)l * D * D,
                                           bl + (size_t)l * D, N);
        cur = o;
    }
}

// Round 2
// 1388.936 us; speedup vs baseline: 2.2429x; 2.2429x over previous
//
#include <hip/hip_runtime.h>

#define D 128
#define TM 16

// ---------------- CSR build ----------------

__global__ void hist_kernel(const int* __restrict__ dst, int* __restrict__ deg, int E) {
    int i = blockIdx.x * blockDim.x + threadIdx.x;
    if (i < E) atomicAdd(&deg[dst[i]], 1);
}

// Two-level scan: scan1 (per-block excl scan + block sums), scan2 (scan block
// sums, single block), scan3 (add base, emit row_start/cursor/inv_deg).

__global__ void scan1_kernel(const int* __restrict__ deg, int* __restrict__ local_excl,
                             int* __restrict__ blocksum, int n) {
    __shared__ int tmp[1024];
    int i = blockIdx.x * 1024 + threadIdx.x;
    int v = (i < n) ? deg[i] : 0;
    tmp[threadIdx.x] = v;
    __syncthreads();
    for (int off = 1; off < 1024; off <<= 1) {
        int t = 0;
        if (threadIdx.x >= off) t = tmp[threadIdx.x - off];
        __syncthreads();
        if (threadIdx.x >= off) tmp[threadIdx.x] += t;
        __syncthreads();
    }
    int incl = tmp[threadIdx.x];
    if (i < n) local_excl[i] = incl - v;
    if (threadIdx.x == 1023) blocksum[blockIdx.x] = tmp[1023];
}

__global__ void scan2_kernel(int* __restrict__ blocksum, int nb) {
    __shared__ int tmp[1024];
    int v = (threadIdx.x < nb) ? blocksum[threadIdx.x] : 0;
    tmp[threadIdx.x] = v;
    __syncthreads();
    for (int off = 1; off < 1024; off <<= 1) {
        int t = 0;
        if (threadIdx.x >= off) t = tmp[threadIdx.x - off];
        __syncthreads();
        if (threadIdx.x >= off) tmp[threadIdx.x] += t;
        __syncthreads();
    }
    if (threadIdx.x < nb) blocksum[threadIdx.x] = tmp[threadIdx.x] - v;  // exclusive
}

__global__ void scan3_kernel(const int* __restrict__ deg, const int* __restrict__ local_excl,
                             const int* __restrict__ blocksum, int* __restrict__ row_start,
                             int* __restrict__ cursor, float* __restrict__ inv_deg,
                             int n, int n_edges) {
    int i = blockIdx.x * 1024 + threadIdx.x;
    if (i < n) {
        int rs = local_excl[i] + blocksum[blockIdx.x];
        row_start[i] = rs;
        cursor[i]    = rs;
        inv_deg[i]   = 1.0f / fmaxf((float)deg[i], 1.0f);
    }
    if (i == 0) row_start[n] = n_edges;
}

__global__ void scatter_kernel(const int* __restrict__ src, const int* __restrict__ dst,
                               int* __restrict__ cursor, int* __restrict__ csr, int E) {
    int i = blockIdx.x * blockDim.x + threadIdx.x;
    if (i < E) {
        int d = dst[i];
        int p = atomicAdd(&cursor[d], 1);
        csr[p] = src[i];
    }
}

// ---------------- weight transpose (W[l][f][k] -> Wt[l][k][f]) ----------------

__global__ void transpose_w(const float* __restrict__ Wl, const float* __restrict__ Wr,
                            float* __restrict__ Wlt, float* __restrict__ Wrt, int total) {
    int i = blockIdx.x * blockDim.x + threadIdx.x;
    if (i < total) {
        int l = i >> 14;
        int r = i & 16383;
        int f = r >> 7;
        int k = r & 127;
        int o = (l << 14) + (k << 7) + f;
        Wlt[o] = Wl[i];
        Wrt[o] = Wr[i];
    }
}

// ---------------- fused SAGE layer: gather-mean + dual GEMM + bias + relu ----------------

__launch_bounds__(256, 4)
__global__ void sage_layer(const float* __restrict__ xin, float* __restrict__ xout,
                           const int* __restrict__ row_start, const int* __restrict__ csr,
                           const float* __restrict__ inv_deg,
                           const float* __restrict__ Wlt, const float* __restrict__ Wrt,
                           const float* __restrict__ bl, int n_nodes) {
    __shared__ __align__(16) float A[TM][D];
    __shared__ __align__(16) float X[TM][D];
    int block0 = blockIdx.x * TM;
    int tid = threadIdx.x;

    // Phase A: one wave per node (4 nodes/wave sequentially). Each wave splits
    // into two 32-lane halves; each half covers the full row (float4/lane) and
    // walks alternate edges with 4 accumulators -> 8 row loads in flight/wave.
    {
        int lane = tid & 63;
        int w    = tid >> 6;      // wave 0..3
        int h    = lane >> 5;     // half 0/1
        int sl   = lane & 31;     // sub-lane within half

        for (int t = 0; t < 4; ++t) {
            int j = w * 4 + t;
            int n = block0 + j;
            float4 s0 = {0,0,0,0}, s1 = {0,0,0,0}, s2 = {0,0,0,0}, s3 = {0,0,0,0};
            float idg = 1.f;
            float2 xv = {0.f, 0.f};
            int e0 = 0, e1 = 0;
            if (n < n_nodes) {
                e0 = row_start[n];
                e1 = row_start[n + 1];
                idg = inv_deg[n];
                xv = ((const float2*)(xin + (size_t)n * D))[lane];
            }
            ((float2*)X[j])[lane] = xv;

            int e = e0 + h;
            for (; e + 6 < e1; e += 8) {
                int i0 = csr[e], i1 = csr[e + 2], i2 = csr[e + 4], i3 = csr[e + 6];
                float4 v0 = ((const float4*)(xin + (size_t)i0 * D))[sl];
                float4 v1 = ((const float4*)(xin + (size_t)i1 * D))[sl];
                float4 v2 = ((const float4*)(xin + (size_t)i2 * D))[sl];
                float4 v3 = ((const float4*)(xin + (size_t)i3 * D))[sl];
                s0.x += v0.x; s0.y += v0.y; s0.z += v0.z; s0.w += v0.w;
                s1.x += v1.x; s1.y += v1.y; s1.z += v1.z; s1.w += v1.w;
                s2.x += v2.x; s2.y += v2.y; s2.z += v2.z; s2.w += v2.w;
                s3.x += v3.x; s3.y += v3.y; s3.z += v3.z; s3.w += v3.w;
            }
            for (; e < e1; e += 2) {
                int i0 = csr[e];
                float4 v0 = ((const float4*)(xin + (size_t)i0 * D))[sl];
                s0.x += v0.x; s0.y += v0.y; s0.z += v0.z; s0.w += v0.w;
            }

            float4 s;
            s.x = (s0.x + s1.x) + (s2.x + s3.x);
            s.y = (s0.y + s1.y) + (s2.y + s3.y);
            s.z = (s0.z + s1.z) + (s2.z + s3.z);
            s.w = (s0.w + s1.w) + (s2.w + s3.w);
            s.x += __shfl_down(s.x, 32);
            s.y += __shfl_down(s.y, 32);
            s.z += __shfl_down(s.z, 32);
            s.w += __shfl_down(s.w, 32);
            if (h == 0) {
                float4 r;
                r.x = s.x * idg; r.y = s.y * idg; r.z = s.z * idg; r.w = s.w * idg;
                ((float4*)A[j])[sl] = r;
            }
        }
    }
    __syncthreads();

    // Phase B: thread tile = 2 nodes x 4 features.
    int tf = tid & 31;        // feature group: f0 = tf*4
    int tn = tid >> 5;        // 0..7
    int j0 = tn * 2;
    const float4* Wlt4 = (const float4*)Wlt;
    const float4* Wrt4 = (const float4*)Wrt;
    float4 bv = ((const float4*)bl)[tf];
    float4 o0 = bv, o1 = bv;
    const float4* A0 = (const float4*)A[j0];
    const float4* A1 = (const float4*)A[j0 + 1];
    const float4* X0 = (const float4*)X[j0];
    const float4* X1 = (const float4*)X[j0 + 1];

    #pragma unroll 4
    for (int kk = 0; kk < 32; ++kk) {
        float4 a0 = A0[kk], a1 = A1[kk], x0 = X0[kk], x1 = X1[kk];
        #pragma unroll
        for (int c = 0; c < 4; ++c) {
            int k = kk * 4 + c;
            float4 wl = Wlt4[k * 32 + tf];
            float4 wr = Wrt4[k * 32 + tf];
            float ac0 = (&a0.x)[c], ac1 = (&a1.x)[c];
            float xc0 = (&x0.x)[c], xc1 = (&x1.x)[c];
            o0.x += wl.x * ac0 + wr.x * xc0;
            o0.y += wl.y * ac0 + wr.y * xc0;
            o0.z += wl.z * ac0 + wr.z * xc0;
            o0.w += wl.w * ac0 + wr.w * xc0;
            o1.x += wl.x * ac1 + wr.x * xc1;
            o1.y += wl.y * ac1 + wr.y * xc1;
            o1.z += wl.z * ac1 + wr.z * xc1;
            o1.w += wl.w * ac1 + wr.w * xc1;
        }
    }

    int n0 = block0 + j0, n1 = n0 + 1;
    if (n0 < n_nodes) {
        float4 r;
        r.x = fmaxf(o0.x, 0.f); r.y = fmaxf(o0.y, 0.f);
        r.z = fmaxf(o0.z, 0.f); r.w = fmaxf(o0.w, 0.f);
        ((float4*)xout)[(size_t)n0 * 32 + tf] = r;
    }
    if (n1 < n_nodes) {
        float4 r;
        r.x = fmaxf(o1.x, 0.f); r.y = fmaxf(o1.y, 0.f);
        r.z = fmaxf(o1.z, 0.f); r.w = fmaxf(o1.w, 0.f);
        ((float4*)xout)[(size_t)n1 * 32 + tf] = r;
    }
}

extern "C" void kernel_launch(void* const* d_in, const int* in_sizes, int n_in,
                              void* d_out, int out_size, void* d_ws, size_t ws_size,
                              hipStream_t stream) {
    const float* x  = (const float*)d_in[0];
    const int*  edge = (const int*)d_in[1];
    const float* Wl = (const float*)d_in[2];
    const float* bl = (const float*)d_in[3];
    const float* Wr = (const float*)d_in[4];

    int N = in_sizes[0] / D;
    int E = in_sizes[1] / 2;
    int L = in_sizes[3] / D;
    const int* srcp = edge;
    const int* dstp = edge + E;

    char* w = (char*)d_ws;
    auto alloc = [&](size_t bytes) {
        char* p = w;
        w += (bytes + 255) & ~(size_t)255;
        return p;
    };
    int*   deg       = (int*)alloc((size_t)N * 4);
    int*   local_ex  = (int*)alloc((size_t)N * 4);
    int*   row_start = (int*)alloc((size_t)(N + 1) * 4);
    int*   cursor    = (int*)alloc((size_t)N * 4);
    int*   csr       = (int*)alloc((size_t)E * 4);
    float* invdeg    = (float*)alloc((size_t)N * 4);
    int*   blocksum  = (int*)alloc((size_t)1024 * 4);
    float* wlt       = (float*)alloc((size_t)L * D * D * 4);
    float* wrt       = (float*)alloc((size_t)L * D * D * 4);
    float* buf0      = (float*)alloc((size_t)N * D * 4);

    int nb1 = (N + 1023) / 1024;
    hipMemsetAsync(deg, 0, (size_t)N * 4, stream);
    hist_kernel<<<(E + 255) / 256, 256, 0, stream>>>(dstp, deg, E);
    scan1_kernel<<<nb1, 1024, 0, stream>>>(deg, local_ex, blocksum, N);
    scan2_kernel<<<1, 1024, 0, stream>>>(blocksum, nb1);
    scan3_kernel<<<nb1, 1024, 0, stream>>>(deg, local_ex, blocksum, row_start,
                                           cursor, invdeg, N, E);
    scatter_kernel<<<(E + 255) / 256, 256, 0, stream>>>(srcp, dstp, cursor, csr, E);
    int tw = L * D * D;
    transpose_w<<<(tw + 255) / 256, 256, 0, stream>>>(Wl, Wr, wlt, wrt, tw);

    float* out = (float*)d_out;
    const float* cur = x;
    int nbl = (N + TM - 1) / TM;
    for (int l = 0; l < L; ++l) {
        float* o = (l & 1) ? out : buf0;
        if (l == L - 1) o = out;
        sage_layer<<<nbl, 256, 0, stream>>>(cur, o, row_start, csr, invdeg,
                                            wlt + (size_t)l * D * D,
                                            wrt + (size_t)l * D * D,
                                            bl + (size_t)l * D, N);
        cur = o;
    }
}